// Round 6
// baseline (655.530 us; speedup 1.0000x reference)
//
#include <hip/hip_runtime.h>
#include <math.h>

#define VOCAB 500
#define EMB   64
#define HID   64
#define BB    512
#define TT    512

// tanh(x) = sign(x) * (1 - 2e/(1+e)), e = exp(-2|x|)  (stable, ~1e-6 abs err)
__device__ __forceinline__ float fast_tanh(float x) {
    float ax = fabsf(x);
    float e  = __expf(-2.0f * ax);
    float r  = __builtin_amdgcn_rcpf(1.0f + e);
    float t  = fmaf(-2.0f * e, r, 1.0f);
    return copysignf(t, x);
}

// proj[v][j] = b_ih0[j] + sum_k W_ih0[j][k] * emb[v][k]
__global__ __launch_bounds__(64) void proj_kernel(
        const float* __restrict__ emb,
        const float* __restrict__ W_ih0,
        const float* __restrict__ b_ih0,
        float* __restrict__ proj) {
    const int v = blockIdx.x;
    const int j = threadIdx.x;
    const float4* e4 = (const float4*)(emb + v * EMB);
    const float4* w4 = (const float4*)(W_ih0 + j * EMB);
    float acc = b_ih0[j];
    #pragma unroll
    for (int k = 0; k < EMB / 4; ++k) {
        float4 e = e4[k];
        float4 w = w4[k];
        acc = fmaf(w.x, e.x, acc);
        acc = fmaf(w.y, e.y, acc);
        acc = fmaf(w.z, e.z, acc);
        acc = fmaf(w.w, e.w, acc);
    }
    proj[v * HID + j] = acc;
}

// One wave (64 lanes) per batch row; lane j owns hidden unit j.
// Recurrent weights resident in VGPRs (launch_bounds(64,1) => up to 512 VGPRs);
// h-state broadcast via LDS; 4-way partial accumulators to cut dep-chain depth.
__global__ __launch_bounds__(64, 1) void rnn_kernel(
        const int*   __restrict__ x,
        const float* __restrict__ proj,
        const float* __restrict__ W_hh0,
        const float* __restrict__ b_hh0,
        const float* __restrict__ W_ih1,
        const float* __restrict__ W_hh1,
        const float* __restrict__ b_ih1,
        const float* __restrict__ b_hh1,
        const float* __restrict__ fc_w,
        const float* __restrict__ fc_b,
        float* __restrict__ out) {
    const int b = blockIdx.x;
    const int j = threadIdx.x;

    __shared__ __align__(16) float h1s[HID];
    __shared__ __align__(16) float h2s[HID];
    __shared__ int xls[TT];

    // stage this row's token indices into LDS
    for (int t = j; t < TT; t += 64) xls[t] = x[b * TT + t];

    // weight rows -> registers (static indices, fully unrolled => VGPRs)
    float whh0[HID], wih1[HID], whh1[HID];
    {
        const float4* a = (const float4*)(W_hh0 + j * HID);
        const float4* c = (const float4*)(W_ih1 + j * HID);
        const float4* d = (const float4*)(W_hh1 + j * HID);
        #pragma unroll
        for (int k = 0; k < HID / 4; ++k) {
            float4 t0 = a[k];
            whh0[4*k+0] = t0.x; whh0[4*k+1] = t0.y; whh0[4*k+2] = t0.z; whh0[4*k+3] = t0.w;
            float4 t1 = c[k];
            wih1[4*k+0] = t1.x; wih1[4*k+1] = t1.y; wih1[4*k+2] = t1.z; wih1[4*k+3] = t1.w;
            float4 t2 = d[k];
            whh1[4*k+0] = t2.x; whh1[4*k+1] = t2.y; whh1[4*k+2] = t2.z; whh1[4*k+3] = t2.w;
        }
    }
    const float bh0 = b_hh0[j];
    const float bi1 = b_ih1[j] + b_hh1[j];
    const float fcw = fc_w[j];

    h1s[j] = 0.0f;
    h2s[j] = 0.0f;
    __syncthreads();

    const float4* h1v = (const float4*)h1s;
    const float4* h2v = (const float4*)h2s;

    int   idx = xls[0];
    float xin = proj[idx * HID + j];   // prefetched input projection for t=0
    float h2n = 0.0f;

    for (int t = 0; t < TT; ++t) {
        // prefetch next step's projected input (hidden under this step's compute)
        const int   idxn = xls[(t + 1) & (TT - 1)];
        const float xinn = proj[idxn * HID + j];

        // 4 independent partial chains per dot product (dep depth 16 not 64)
        float a1p0 = xin, a1p1 = bh0, a1p2 = 0.0f, a1p3 = 0.0f;
        float a2p0 = bi1, a2p1 = 0.0f, a2p2 = 0.0f, a2p3 = 0.0f;
        #pragma unroll
        for (int k = 0; k < HID / 4; ++k) {
            float4 h = h1v[k];   // old h1 (uniform address -> broadcast)
            a1p0 = fmaf(whh0[4*k+0], h.x, a1p0);
            a1p1 = fmaf(whh0[4*k+1], h.y, a1p1);
            a1p2 = fmaf(whh0[4*k+2], h.z, a1p2);
            a1p3 = fmaf(whh0[4*k+3], h.w, a1p3);
            float4 g = h2v[k];   // old h2
            a2p0 = fmaf(whh1[4*k+0], g.x, a2p0);
            a2p1 = fmaf(whh1[4*k+1], g.y, a2p1);
            a2p2 = fmaf(whh1[4*k+2], g.z, a2p2);
            a2p3 = fmaf(whh1[4*k+3], g.w, a2p3);
        }
        const float h1n = fast_tanh((a1p0 + a1p1) + (a1p2 + a1p3));

        __syncthreads();          // (A) all lanes done reading old h1s/h2s
        h1s[j] = h1n;
        __syncthreads();          // (B) new h1 visible

        float b0 = a2p0, b1 = a2p1, b2 = a2p2, b3 = a2p3;
        #pragma unroll
        for (int k = 0; k < HID / 4; ++k) {
            float4 h = h1v[k];    // new h1
            b0 = fmaf(wih1[4*k+0], h.x, b0);
            b1 = fmaf(wih1[4*k+1], h.y, b1);
            b2 = fmaf(wih1[4*k+2], h.z, b2);
            b3 = fmaf(wih1[4*k+3], h.w, b3);
        }
        h2n = fast_tanh((b0 + b1) + (b2 + b3));
        h2s[j] = h2n;             // old h2s reads all finished before (A)
        __syncthreads();          // (C) new h2 visible for next iteration

        xin = xinn;
    }

    // out[b] = fc_b + sum_j h2[j] * fc_w[j]
    float val = h2n * fcw;
    #pragma unroll
    for (int o = 32; o > 0; o >>= 1) val += __shfl_down(val, o, 64);
    if (j == 0) out[b] = val + fc_b[0];
}

extern "C" void kernel_launch(void* const* d_in, const int* in_sizes, int n_in,
                              void* d_out, int out_size, void* d_ws, size_t ws_size,
                              hipStream_t stream) {
    const int*   x     = (const int*)  d_in[0];
    const float* emb   = (const float*)d_in[1];
    const float* W_ih0 = (const float*)d_in[2];
    const float* W_hh0 = (const float*)d_in[3];
    const float* b_ih0 = (const float*)d_in[4];
    const float* b_hh0 = (const float*)d_in[5];
    const float* W_ih1 = (const float*)d_in[6];
    const float* W_hh1 = (const float*)d_in[7];
    const float* b_ih1 = (const float*)d_in[8];
    const float* b_hh1 = (const float*)d_in[9];
    const float* fc_w  = (const float*)d_in[10];
    const float* fc_b  = (const float*)d_in[11];
    float* out  = (float*)d_out;
    float* proj = (float*)d_ws;   // 500*64*4 = 128 KB scratch

    proj_kernel<<<VOCAB, 64, 0, stream>>>(emb, W_ih0, b_ih0, proj);
    rnn_kernel<<<BB, 64, 0, stream>>>(x, proj, W_hh0, b_hh0,
                                      W_ih1, W_hh1, b_ih1, b_hh1,
                                      fc_w, fc_b, out);
}

// Round 7
// 592.182 us; speedup vs baseline: 1.1070x; 1.1070x over previous
//
#include <hip/hip_runtime.h>
#include <math.h>

#define VOCAB 500
#define EMB   64
#define HID   64
#define BB    512
#define TT    512

// tanh(x) = sign(x) * (1 - 2e/(1+e)), e = exp(-2|x|)  (stable, ~1e-6 abs err)
__device__ __forceinline__ float fast_tanh(float x) {
    float ax = fabsf(x);
    float e  = __expf(-2.0f * ax);
    float r  = __builtin_amdgcn_rcpf(1.0f + e);
    float t  = fmaf(-2.0f * e, r, 1.0f);
    return copysignf(t, x);
}

// proj[v][j] = b_ih0[j] + sum_k W_ih0[j][k] * emb[v][k]
__global__ __launch_bounds__(64) void proj_kernel(
        const float* __restrict__ emb,
        const float* __restrict__ W_ih0,
        const float* __restrict__ b_ih0,
        float* __restrict__ proj) {
    const int v = blockIdx.x;
    const int j = threadIdx.x;
    const float4* e4 = (const float4*)(emb + v * EMB);
    const float4* w4 = (const float4*)(W_ih0 + j * EMB);
    float acc = b_ih0[j];
    #pragma unroll
    for (int k = 0; k < EMB / 4; ++k) {
        float4 e = e4[k];
        float4 w = w4[k];
        acc = fmaf(w.x, e.x, acc);
        acc = fmaf(w.y, e.y, acc);
        acc = fmaf(w.z, e.z, acc);
        acc = fmaf(w.w, e.w, acc);
    }
    proj[v * HID + j] = acc;
}

// One wave (64 lanes) per batch row; lane j owns hidden unit j.
// Weight rows loaded ONCE and pinned into VGPRs via empty asm (compiler cannot
// rematerialize the loads inside the 512-step loop). h-state ping-pong in LDS
// (2 barriers/step). 4-way partial accumulators cut FMA dep-chain to 16.
__global__ __launch_bounds__(64, 1) void rnn_kernel(
        const int*   __restrict__ x,
        const float* __restrict__ proj,
        const float* __restrict__ W_hh0,
        const float* __restrict__ b_hh0,
        const float* __restrict__ W_ih1,
        const float* __restrict__ W_hh1,
        const float* __restrict__ b_ih1,
        const float* __restrict__ b_hh1,
        const float* __restrict__ fc_w,
        const float* __restrict__ fc_b,
        float* __restrict__ out) {
    const int b = blockIdx.x;
    const int j = threadIdx.x;

    __shared__ __align__(16) float H1[2][HID];
    __shared__ __align__(16) float H2[2][HID];
    __shared__ int xls[TT];

    // stage this row's token indices into LDS
    for (int t = j; t < TT; t += 64) xls[t] = x[b * TT + t];

    // weight rows -> registers (static indices, fully unrolled)
    float whh0[HID], wih1[HID], whh1[HID];
    {
        const float4* a = (const float4*)(W_hh0 + j * HID);
        const float4* c = (const float4*)(W_ih1 + j * HID);
        const float4* d = (const float4*)(W_hh1 + j * HID);
        #pragma unroll
        for (int k = 0; k < HID / 4; ++k) {
            float4 t0 = a[k];
            whh0[4*k+0] = t0.x; whh0[4*k+1] = t0.y; whh0[4*k+2] = t0.z; whh0[4*k+3] = t0.w;
            float4 t1 = c[k];
            wih1[4*k+0] = t1.x; wih1[4*k+1] = t1.y; wih1[4*k+2] = t1.z; wih1[4*k+3] = t1.w;
            float4 t2 = d[k];
            whh1[4*k+0] = t2.x; whh1[4*k+1] = t2.y; whh1[4*k+2] = t2.z; whh1[4*k+3] = t2.w;
        }
    }
    // PIN: make every weight opaque so the compiler cannot sink the loads
    // back into the time loop. Values must stay VGPR-resident.
    #pragma unroll
    for (int k = 0; k < HID; ++k) {
        asm volatile("" : "+v"(whh0[k]), "+v"(wih1[k]), "+v"(whh1[k]));
    }

    const float bh0 = b_hh0[j];
    const float bi1 = b_ih1[j] + b_hh1[j];
    const float fcw = fc_w[j];

    H1[0][j] = 0.0f; H1[1][j] = 0.0f;
    H2[0][j] = 0.0f; H2[1][j] = 0.0f;
    __syncthreads();

    int   idx = xls[0];
    float xin = proj[idx * HID + j];   // prefetched input projection for t=0
    float h2n = 0.0f;

    for (int t = 0; t < TT; ++t) {
        const int cur = t & 1;
        const int prv = cur ^ 1;
        const float4* h1old = (const float4*)H1[prv];
        const float4* h2old = (const float4*)H2[prv];
        const float4* h1new = (const float4*)H1[cur];

        // prefetch next step's projected input (hidden under this step's compute)
        const int   idxn = xls[(t + 1) & (TT - 1)];
        const float xinn = proj[idxn * HID + j];

        // 4 independent partial chains per dot product (dep depth 16 not 64)
        float a1p0 = xin, a1p1 = bh0, a1p2 = 0.0f, a1p3 = 0.0f;
        float a2p0 = bi1, a2p1 = 0.0f, a2p2 = 0.0f, a2p3 = 0.0f;
        #pragma unroll
        for (int k = 0; k < HID / 4; ++k) {
            float4 h = h1old[k];   // old h1 (uniform address -> broadcast)
            a1p0 = fmaf(whh0[4*k+0], h.x, a1p0);
            a1p1 = fmaf(whh0[4*k+1], h.y, a1p1);
            a1p2 = fmaf(whh0[4*k+2], h.z, a1p2);
            a1p3 = fmaf(whh0[4*k+3], h.w, a1p3);
            float4 g = h2old[k];   // old h2
            a2p0 = fmaf(whh1[4*k+0], g.x, a2p0);
            a2p1 = fmaf(whh1[4*k+1], g.y, a2p1);
            a2p2 = fmaf(whh1[4*k+2], g.z, a2p2);
            a2p3 = fmaf(whh1[4*k+3], g.w, a2p3);
        }
        const float h1n = fast_tanh((a1p0 + a1p1) + (a1p2 + a1p3));

        H1[cur][j] = h1n;         // old buffers untouched -> no pre-write barrier
        __syncthreads();          // (B) new h1 visible

        float b0 = a2p0, b1 = a2p1, b2 = a2p2, b3 = a2p3;
        #pragma unroll
        for (int k = 0; k < HID / 4; ++k) {
            float4 h = h1new[k];  // new h1
            b0 = fmaf(wih1[4*k+0], h.x, b0);
            b1 = fmaf(wih1[4*k+1], h.y, b1);
            b2 = fmaf(wih1[4*k+2], h.z, b2);
            b3 = fmaf(wih1[4*k+3], h.w, b3);
        }
        h2n = fast_tanh((b0 + b1) + (b2 + b3));
        H2[cur][j] = h2n;
        __syncthreads();          // (C) new h2 visible for next iteration

        xin = xinn;
    }

    // out[b] = fc_b + sum_j h2[j] * fc_w[j]
    float val = h2n * fcw;
    #pragma unroll
    for (int o = 32; o > 0; o >>= 1) val += __shfl_down(val, o, 64);
    if (j == 0) out[b] = val + fc_b[0];
}

extern "C" void kernel_launch(void* const* d_in, const int* in_sizes, int n_in,
                              void* d_out, int out_size, void* d_ws, size_t ws_size,
                              hipStream_t stream) {
    const int*   x     = (const int*)  d_in[0];
    const float* emb   = (const float*)d_in[1];
    const float* W_ih0 = (const float*)d_in[2];
    const float* W_hh0 = (const float*)d_in[3];
    const float* b_ih0 = (const float*)d_in[4];
    const float* b_hh0 = (const float*)d_in[5];
    const float* W_ih1 = (const float*)d_in[6];
    const float* W_hh1 = (const float*)d_in[7];
    const float* b_ih1 = (const float*)d_in[8];
    const float* b_hh1 = (const float*)d_in[9];
    const float* fc_w  = (const float*)d_in[10];
    const float* fc_b  = (const float*)d_in[11];
    float* out  = (float*)d_out;
    float* proj = (float*)d_ws;   // 500*64*4 = 128 KB scratch

    proj_kernel<<<VOCAB, 64, 0, stream>>>(emb, W_ih0, b_ih0, proj);
    rnn_kernel<<<BB, 64, 0, stream>>>(x, proj, W_hh0, b_hh0,
                                      W_ih1, W_hh1, b_ih1, b_hh1,
                                      fc_w, fc_b, out);
}

// Round 9
// 478.610 us; speedup vs baseline: 1.3697x; 1.2373x over previous
//
#include <hip/hip_runtime.h>
#include <math.h>

#define VOCAB 500
#define EMB   64
#define HID   64
#define BB    512
#define TT    512

// tanh(x) = sign(x) * (1 - 2e/(1+e)), e = exp(-2|x|)  (stable, ~1e-6 abs err)
__device__ __forceinline__ float fast_tanh(float x) {
    float ax = fabsf(x);
    float e  = __expf(-2.0f * ax);
    float r  = __builtin_amdgcn_rcpf(1.0f + e);
    float t  = fmaf(-2.0f * e, r, 1.0f);
    return copysignf(t, x);
}

// proj[v][j] = b_ih0[j] + sum_k W_ih0[j][k] * emb[v][k]
__global__ __launch_bounds__(64) void proj_kernel(
        const float* __restrict__ emb,
        const float* __restrict__ W_ih0,
        const float* __restrict__ b_ih0,
        float* __restrict__ proj) {
    const int v = blockIdx.x;
    const int j = threadIdx.x;
    const float4* e4 = (const float4*)(emb + v * EMB);
    const float4* w4 = (const float4*)(W_ih0 + j * EMB);
    float acc = b_ih0[j];
    #pragma unroll
    for (int k = 0; k < EMB / 4; ++k) {
        float4 e = e4[k];
        float4 w = w4[k];
        acc = fmaf(w.x, e.x, acc);
        acc = fmaf(w.y, e.y, acc);
        acc = fmaf(w.z, e.z, acc);
        acc = fmaf(w.w, e.w, acc);
    }
    proj[v * HID + j] = acc;
}

// 3 waves per block, one batch row per block. Lane j of each wave owns hidden
// unit j of ONE matvec (64 weight floats/lane -> ~100 VGPR, no spill):
//   wave0: h1_new = tanh(xin + W_hh0 . h1_old + b_hh0)      (phase A)
//   wave2: p2     = W_hh1 . h2_old                          (phase A, parallel)
//   wave1: h2_new = tanh(W_ih1 . h1_new + p2 + b_ih1+b_hh1) (phase B)
// h-state ping-pong in LDS; 2 barriers/step; uniform-address (broadcast) reads.
__global__ __launch_bounds__(192, 1) void rnn_kernel(
        const int*   __restrict__ x,
        const float* __restrict__ proj,
        const float* __restrict__ W_hh0,
        const float* __restrict__ b_hh0,
        const float* __restrict__ W_ih1,
        const float* __restrict__ W_hh1,
        const float* __restrict__ b_ih1,
        const float* __restrict__ b_hh1,
        const float* __restrict__ fc_w,
        const float* __restrict__ fc_b,
        float* __restrict__ out) {
    const int b   = blockIdx.x;
    const int tid = threadIdx.x;
    const int wid = tid >> 6;     // 0,1,2 (wave-uniform)
    const int j   = tid & 63;     // hidden unit

    __shared__ __align__(16) float H1[2][HID];
    __shared__ __align__(16) float H2[2][HID];
    __shared__ __align__(16) float P2[HID];
    __shared__ int xls[TT];

    // stage this row's token indices into LDS
    for (int t = tid; t < TT; t += 192) xls[t] = x[b * TT + t];

    // each wave loads ONE weight row into registers (16 float4, static unroll)
    const float* wsrc = (wid == 0 ? W_hh0 : (wid == 1 ? W_ih1 : W_hh1)) + j * HID;
    float w[HID];
    {
        const float4* w4 = (const float4*)wsrc;
        #pragma unroll
        for (int k = 0; k < HID / 4; ++k) {
            float4 t4 = w4[k];
            w[4*k+0] = t4.x; w[4*k+1] = t4.y; w[4*k+2] = t4.z; w[4*k+3] = t4.w;
        }
    }
    // pin: forbid re-loading inside the time loop
    #pragma unroll
    for (int k = 0; k < HID; ++k) asm volatile("" : "+v"(w[k]));

    const float bh0 = b_hh0[j];
    const float bi1 = b_ih1[j] + b_hh1[j];
    const float fcw = fc_w[j];

    if (tid < HID) {
        H1[0][tid] = 0.0f; H1[1][tid] = 0.0f;
        H2[0][tid] = 0.0f; H2[1][tid] = 0.0f;
    }
    __syncthreads();

    float xin = (wid == 0) ? proj[xls[0] * HID + j] : 0.0f;
    float h2n = 0.0f;

    for (int t = 0; t < TT; ++t) {
        const int cur = t & 1;
        const int prv = cur ^ 1;

        if (wid == 0) {
            // prefetch next step's projected input
            const int   idxn = xls[(t + 1) & (TT - 1)];
            const float xinn = proj[idxn * HID + j];

            const float4* h = (const float4*)H1[prv];
            float p0 = xin + bh0, p1 = 0.0f, p2 = 0.0f, p3 = 0.0f;
            #pragma unroll
            for (int k = 0; k < HID / 4; ++k) {
                float4 hv = h[k];           // uniform address -> LDS broadcast
                p0 = fmaf(w[4*k+0], hv.x, p0);
                p1 = fmaf(w[4*k+1], hv.y, p1);
                p2 = fmaf(w[4*k+2], hv.z, p2);
                p3 = fmaf(w[4*k+3], hv.w, p3);
            }
            H1[cur][j] = fast_tanh((p0 + p1) + (p2 + p3));
            xin = xinn;
        } else if (wid == 2) {
            const float4* h = (const float4*)H2[prv];
            float p0 = 0.0f, p1 = 0.0f, p2 = 0.0f, p3 = 0.0f;
            #pragma unroll
            for (int k = 0; k < HID / 4; ++k) {
                float4 hv = h[k];
                p0 = fmaf(w[4*k+0], hv.x, p0);
                p1 = fmaf(w[4*k+1], hv.y, p1);
                p2 = fmaf(w[4*k+2], hv.z, p2);
                p3 = fmaf(w[4*k+3], hv.w, p3);
            }
            P2[j] = (p0 + p1) + (p2 + p3);
        }
        __syncthreads();                    // h1_new + p2 visible

        if (wid == 1) {
            const float4* h = (const float4*)H1[cur];
            float p0 = bi1 + P2[j], p1 = 0.0f, p2 = 0.0f, p3 = 0.0f;
            #pragma unroll
            for (int k = 0; k < HID / 4; ++k) {
                float4 hv = h[k];
                p0 = fmaf(w[4*k+0], hv.x, p0);
                p1 = fmaf(w[4*k+1], hv.y, p1);
                p2 = fmaf(w[4*k+2], hv.z, p2);
                p3 = fmaf(w[4*k+3], hv.w, p3);
            }
            h2n = fast_tanh((p0 + p1) + (p2 + p3));
            H2[cur][j] = h2n;
        }
        __syncthreads();                    // h2_new visible for next step
    }

    // out[b] = fc_b + sum_j h2[j] * fc_w[j]   (wave1 holds h2n)
    if (wid == 1) {
        float val = h2n * fcw;
        #pragma unroll
        for (int o = 32; o > 0; o >>= 1) val += __shfl_down(val, o, 64);
        if (j == 0) out[b] = val + fc_b[0];
    }
}

extern "C" void kernel_launch(void* const* d_in, const int* in_sizes, int n_in,
                              void* d_out, int out_size, void* d_ws, size_t ws_size,
                              hipStream_t stream) {
    const int*   x     = (const int*)  d_in[0];
    const float* emb   = (const float*)d_in[1];
    const float* W_ih0 = (const float*)d_in[2];
    const float* W_hh0 = (const float*)d_in[3];
    const float* b_ih0 = (const float*)d_in[4];
    const float* b_hh0 = (const float*)d_in[5];
    const float* W_ih1 = (const float*)d_in[6];
    const float* W_hh1 = (const float*)d_in[7];
    const float* b_ih1 = (const float*)d_in[8];
    const float* b_hh1 = (const float*)d_in[9];
    const float* fc_w  = (const float*)d_in[10];
    const float* fc_b  = (const float*)d_in[11];
    float* out  = (float*)d_out;
    float* proj = (float*)d_ws;   // 500*64*4 = 128 KB scratch

    proj_kernel<<<VOCAB, 64, 0, stream>>>(emb, W_ih0, b_ih0, proj);
    rnn_kernel<<<BB, 192, 0, stream>>>(x, proj, W_hh0, b_hh0,
                                       W_ih1, W_hh1, b_ih1, b_hh1,
                                       fc_w, fc_b, out);
}

// Round 10
// 323.232 us; speedup vs baseline: 2.0280x; 1.4807x over previous
//
#include <hip/hip_runtime.h>
#include <math.h>

#define VOCAB 500
#define EMB   64
#define HID   64
#define BB    512
#define TT    512

// tanh(x) = sign(x) * (1 - 2e/(1+e)), e = exp(-2|x|)  (stable, ~1e-6 abs err)
__device__ __forceinline__ float fast_tanh(float x) {
    float ax = fabsf(x);
    float e  = __expf(-2.0f * ax);
    float r  = __builtin_amdgcn_rcpf(1.0f + e);
    float t  = fmaf(-2.0f * e, r, 1.0f);
    return copysignf(t, x);
}

// proj[v][j] = b_ih0[j] + sum_k W_ih0[j][k] * emb[v][k]
__global__ __launch_bounds__(64) void proj_kernel(
        const float* __restrict__ emb,
        const float* __restrict__ W_ih0,
        const float* __restrict__ b_ih0,
        float* __restrict__ proj) {
    const int v = blockIdx.x;
    const int j = threadIdx.x;
    const float4* e4 = (const float4*)(emb + v * EMB);
    const float4* w4 = (const float4*)(W_ih0 + j * EMB);
    float acc = b_ih0[j];
    #pragma unroll
    for (int k = 0; k < EMB / 4; ++k) {
        float4 e = e4[k];
        float4 w = w4[k];
        acc = fmaf(w.x, e.x, acc);
        acc = fmaf(w.y, e.y, acc);
        acc = fmaf(w.z, e.z, acc);
        acc = fmaf(w.w, e.w, acc);
    }
    proj[v * HID + j] = acc;
}

// Software-pipelined 2-layer RNN: 3 waves/block, ONE barrier per phase.
// Phase p:
//   wave0: h1[p]   = tanh(xin[p] + W_hh0 . h1[p-1] + b_hh0)
//   wave1: A[p-1]  = W_ih1 . h1[p-1]
//   wave2: h2[p-2] = tanh(A[p-2] + W_hh1 . h2[p-3] + b_ih1 + b_hh1)
// Every wave reads only phase-(p-1) outputs -> single barrier, parallel matvecs.
// Buffers ping-pong on phase parity; each lane holds one 64-float weight row.
__global__ __launch_bounds__(192, 1) void rnn_kernel(
        const int*   __restrict__ x,
        const float* __restrict__ proj,
        const float* __restrict__ W_hh0,
        const float* __restrict__ b_hh0,
        const float* __restrict__ W_ih1,
        const float* __restrict__ W_hh1,
        const float* __restrict__ b_ih1,
        const float* __restrict__ b_hh1,
        const float* __restrict__ fc_w,
        const float* __restrict__ fc_b,
        float* __restrict__ out) {
    const int b   = blockIdx.x;
    const int tid = threadIdx.x;
    const int wid = tid >> 6;     // 0,1,2 (wave-uniform)
    const int j   = tid & 63;     // hidden unit

    __shared__ __align__(16) float H1[2][HID];
    __shared__ __align__(16) float H2[2][HID];
    __shared__ __align__(16) float AA[2][HID];
    __shared__ int xls[TT];

    // stage this row's token indices into LDS
    for (int t = tid; t < TT; t += 192) xls[t] = x[b * TT + t];

    // each wave loads ONE weight row into registers (16 float4, static unroll)
    const float* wsrc = (wid == 0 ? W_hh0 : (wid == 1 ? W_ih1 : W_hh1)) + j * HID;
    float w[HID];
    {
        const float4* w4 = (const float4*)wsrc;
        #pragma unroll
        for (int k = 0; k < HID / 4; ++k) {
            float4 t4 = w4[k];
            w[4*k+0] = t4.x; w[4*k+1] = t4.y; w[4*k+2] = t4.z; w[4*k+3] = t4.w;
        }
    }
    // pin: forbid re-loading inside the time loop
    #pragma unroll
    for (int k = 0; k < HID; ++k) asm volatile("" : "+v"(w[k]));

    const float bh0 = b_hh0[j];
    const float bi1 = b_ih1[j] + b_hh1[j];
    const float fcw = fc_w[j];

    if (tid < HID) {
        H1[0][tid] = 0.0f; H1[1][tid] = 0.0f;
        H2[0][tid] = 0.0f; H2[1][tid] = 0.0f;
    }
    __syncthreads();

    float xin = (wid == 0) ? proj[xls[0] * HID + j] : 0.0f;
    float h2n = 0.0f;

    for (int p = 0; p < TT + 2; ++p) {
        const int cur = p & 1;
        const int prv = cur ^ 1;

        if (wid == 0) {
            if (p < TT) {
                // prefetch next phase's projected input
                const int   idxn = xls[(p + 1) & (TT - 1)];
                const float xinn = proj[idxn * HID + j];

                const float4* h = (const float4*)H1[prv];   // h1[p-1]
                float p0 = xin + bh0, p1 = 0.0f, p2 = 0.0f, p3 = 0.0f;
                #pragma unroll
                for (int k = 0; k < HID / 4; ++k) {
                    float4 hv = h[k];       // uniform address -> LDS broadcast
                    p0 = fmaf(w[4*k+0], hv.x, p0);
                    p1 = fmaf(w[4*k+1], hv.y, p1);
                    p2 = fmaf(w[4*k+2], hv.z, p2);
                    p3 = fmaf(w[4*k+3], hv.w, p3);
                }
                H1[cur][j] = fast_tanh((p0 + p1) + (p2 + p3));
                xin = xinn;
            }
        } else if (wid == 1) {
            if (p >= 1 && p <= TT) {
                const float4* h = (const float4*)H1[prv];   // h1[p-1]
                float p0 = 0.0f, p1 = 0.0f, p2 = 0.0f, p3 = 0.0f;
                #pragma unroll
                for (int k = 0; k < HID / 4; ++k) {
                    float4 hv = h[k];
                    p0 = fmaf(w[4*k+0], hv.x, p0);
                    p1 = fmaf(w[4*k+1], hv.y, p1);
                    p2 = fmaf(w[4*k+2], hv.z, p2);
                    p3 = fmaf(w[4*k+3], hv.w, p3);
                }
                AA[prv][j] = (p0 + p1) + (p2 + p3);         // A[p-1]
            }
        } else {
            if (p >= 2) {
                const float4* h = (const float4*)H2[prv];   // h2[p-3]
                float p0 = bi1 + AA[cur][j], p1 = 0.0f, p2 = 0.0f, p3 = 0.0f;
                #pragma unroll
                for (int k = 0; k < HID / 4; ++k) {
                    float4 hv = h[k];
                    p0 = fmaf(w[4*k+0], hv.x, p0);
                    p1 = fmaf(w[4*k+1], hv.y, p1);
                    p2 = fmaf(w[4*k+2], hv.z, p2);
                    p3 = fmaf(w[4*k+3], hv.w, p3);
                }
                h2n = fast_tanh((p0 + p1) + (p2 + p3));     // h2[p-2]
                H2[cur][j] = h2n;
            }
        }
        __syncthreads();
    }

    // out[b] = fc_b + sum_j h2[TT-1][j] * fc_w[j]   (wave2 holds h2n)
    if (wid == 2) {
        float val = h2n * fcw;
        #pragma unroll
        for (int o = 32; o > 0; o >>= 1) val += __shfl_down(val, o, 64);
        if (j == 0) out[b] = val + fc_b[0];
    }
}

extern "C" void kernel_launch(void* const* d_in, const int* in_sizes, int n_in,
                              void* d_out, int out_size, void* d_ws, size_t ws_size,
                              hipStream_t stream) {
    const int*   x     = (const int*)  d_in[0];
    const float* emb   = (const float*)d_in[1];
    const float* W_ih0 = (const float*)d_in[2];
    const float* W_hh0 = (const float*)d_in[3];
    const float* b_ih0 = (const float*)d_in[4];
    const float* b_hh0 = (const float*)d_in[5];
    const float* W_ih1 = (const float*)d_in[6];
    const float* W_hh1 = (const float*)d_in[7];
    const float* b_ih1 = (const float*)d_in[8];
    const float* b_hh1 = (const float*)d_in[9];
    const float* fc_w  = (const float*)d_in[10];
    const float* fc_b  = (const float*)d_in[11];
    float* out  = (float*)d_out;
    float* proj = (float*)d_ws;   // 500*64*4 = 128 KB scratch

    proj_kernel<<<VOCAB, 64, 0, stream>>>(emb, W_ih0, b_ih0, proj);
    rnn_kernel<<<BB, 192, 0, stream>>>(x, proj, W_hh0, b_hh0,
                                       W_ih1, W_hh1, b_ih1, b_hh1,
                                       fc_w, fc_b, out);
}

// Round 12
// 318.412 us; speedup vs baseline: 2.0587x; 1.0151x over previous
//
#include <hip/hip_runtime.h>
#include <math.h>

#define VOCAB 500
#define EMB   64
#define HID   64
#define BB    512
#define TT    512
#define KC    8           // steps per chunk (barrier period)
#define NC    (TT / KC)   // 64 chunks

// tanh(x) = sign(x) * (1 - 2e/(1+e)), e = exp(-2|x|)  (stable, ~1e-6 abs err)
__device__ __forceinline__ float fast_tanh(float x) {
    float ax = fabsf(x);
    float e  = __expf(-2.0f * ax);
    float r  = __builtin_amdgcn_rcpf(1.0f + e);
    float t  = fmaf(-2.0f * e, r, 1.0f);
    return copysignf(t, x);
}

// in-wave broadcast of lane `lane`'s value (compile-time lane) via v_readlane
__device__ __forceinline__ float bcast(float v, int lane) {
    return __int_as_float(__builtin_amdgcn_readlane(__float_as_int(v), lane));
}

// proj[v][j] = b_ih0[j] + sum_k W_ih0[j][k] * emb[v][k]
__global__ __launch_bounds__(64) void proj_kernel(
        const float* __restrict__ emb,
        const float* __restrict__ W_ih0,
        const float* __restrict__ b_ih0,
        float* __restrict__ proj) {
    const int v = blockIdx.x;
    const int j = threadIdx.x;
    const float4* e4 = (const float4*)(emb + v * EMB);
    const float4* w4 = (const float4*)(W_ih0 + j * EMB);
    float acc = b_ih0[j];
    #pragma unroll
    for (int k = 0; k < EMB / 4; ++k) {
        float4 e = e4[k];
        float4 w = w4[k];
        acc = fmaf(w.x, e.x, acc);
        acc = fmaf(w.y, e.y, acc);
        acc = fmaf(w.z, e.z, acc);
        acc = fmaf(w.w, e.w, acc);
    }
    proj[v * HID + j] = acc;
}

// Chunked software pipeline, 3 waves/block, ONE barrier per KC steps.
// Phase c:
//   wave0: h1 recurrence for chunk c      (self-broadcast via readlane,
//          writes h1 vectors to H1R[c&1] for wave1)
//   wave1: A[s] = W_ih1 . h1[s], chunk c-1 (LDS broadcast reads, independent
//          steps -> fully pipelined; writes AAR[(c-1)&1])
//   wave2: h2 recurrence for chunk c-2    (reads A per-lane, self-broadcast
//          via readlane)
// Ring parities: wave0 W H1R[c&1] / wave1 R H1R[(c-1)&1]  (opposite)
//                wave1 W AAR[(c-1)&1] / wave2 R AAR[c&1]  (opposite)
__global__ __launch_bounds__(192, 1) void rnn_kernel(
        const int*   __restrict__ x,
        const float* __restrict__ proj,
        const float* __restrict__ W_hh0,
        const float* __restrict__ b_hh0,
        const float* __restrict__ W_ih1,
        const float* __restrict__ W_hh1,
        const float* __restrict__ b_ih1,
        const float* __restrict__ b_hh1,
        const float* __restrict__ fc_w,
        const float* __restrict__ fc_b,
        float* __restrict__ out) {
    const int b   = blockIdx.x;
    const int tid = threadIdx.x;
    const int wid = tid >> 6;     // 0,1,2 (wave-uniform)
    const int j   = tid & 63;     // hidden unit

    __shared__ __align__(16) float H1R[2][KC][HID];
    __shared__ __align__(16) float AAR[2][KC][HID];
    __shared__ int xls[TT];

    // stage this row's token indices into LDS
    for (int t = tid; t < TT; t += 192) xls[t] = x[b * TT + t];

    // each wave loads ONE weight row into registers (16 float4, static unroll)
    const float* wsrc = (wid == 0 ? W_hh0 : (wid == 1 ? W_ih1 : W_hh1)) + j * HID;
    float w[HID];
    {
        const float4* w4 = (const float4*)wsrc;
        #pragma unroll
        for (int k = 0; k < HID / 4; ++k) {
            float4 t4 = w4[k];
            w[4*k+0] = t4.x; w[4*k+1] = t4.y; w[4*k+2] = t4.z; w[4*k+3] = t4.w;
        }
    }
    // pin: forbid re-loading inside the time loop
    #pragma unroll
    for (int k = 0; k < HID; ++k) asm volatile("" : "+v"(w[k]));

    const float bh0 = b_hh0[j];
    const float bi1 = b_ih1[j] + b_hh1[j];
    const float fcw = fc_w[j];

    __syncthreads();   // xls visible

    float h1reg = 0.0f, h2reg = 0.0f;
    float xin[KC], xinN[KC];
    if (wid == 0) {
        #pragma unroll
        for (int u = 0; u < KC; ++u) xin[u] = proj[xls[u] * HID + j];
    }

    for (int c = 0; c < NC + 2; ++c) {
        if (wid == 0) {
            if (c < NC) {
                // issue next chunk's gathers first (latency hides under compute)
                const int base = ((c + 1) & (NC - 1)) * KC;
                #pragma unroll
                for (int u = 0; u < KC; ++u)
                    xinN[u] = proj[xls[base + u] * HID + j];

                #pragma unroll
                for (int u = 0; u < KC; ++u) {
                    float a0 = xin[u] + bh0, a1 = 0.0f, a2 = 0.0f, a3 = 0.0f;
                    #pragma unroll
                    for (int k = 0; k < HID; k += 4) {
                        a0 = fmaf(w[k+0], bcast(h1reg, k+0), a0);
                        a1 = fmaf(w[k+1], bcast(h1reg, k+1), a1);
                        a2 = fmaf(w[k+2], bcast(h1reg, k+2), a2);
                        a3 = fmaf(w[k+3], bcast(h1reg, k+3), a3);
                    }
                    h1reg = fast_tanh((a0 + a1) + (a2 + a3));
                    H1R[c & 1][u][j] = h1reg;
                    xin[u] = xinN[u];
                }
            }
        } else if (wid == 1) {
            if (c >= 1 && c <= NC) {
                const int p = (c - 1) & 1;
                #pragma unroll
                for (int u = 0; u < KC; ++u) {
                    const float4* hv = (const float4*)(&H1R[p][u][0]);
                    float a0 = 0.0f, a1 = 0.0f, a2 = 0.0f, a3 = 0.0f;
                    #pragma unroll
                    for (int k = 0; k < HID / 4; ++k) {
                        float4 h = hv[k];       // uniform addr -> broadcast
                        a0 = fmaf(w[4*k+0], h.x, a0);
                        a1 = fmaf(w[4*k+1], h.y, a1);
                        a2 = fmaf(w[4*k+2], h.z, a2);
                        a3 = fmaf(w[4*k+3], h.w, a3);
                    }
                    AAR[p][u][j] = (a0 + a1) + (a2 + a3);
                }
            }
        } else {
            if (c >= 2) {
                const int p = c & 1;        // == (c-2)&1
                #pragma unroll
                for (int u = 0; u < KC; ++u) {
                    float a0 = AAR[p][u][j] + bi1, a1 = 0.0f, a2 = 0.0f, a3 = 0.0f;
                    #pragma unroll
                    for (int k = 0; k < HID; k += 4) {
                        a0 = fmaf(w[k+0], bcast(h2reg, k+0), a0);
                        a1 = fmaf(w[k+1], bcast(h2reg, k+1), a1);
                        a2 = fmaf(w[k+2], bcast(h2reg, k+2), a2);
                        a3 = fmaf(w[k+3], bcast(h2reg, k+3), a3);
                    }
                    h2reg = fast_tanh((a0 + a1) + (a2 + a3));
                }
            }
        }
        __syncthreads();
    }

    // out[b] = fc_b + sum_j h2[TT-1][j] * fc_w[j]   (wave2 holds h2reg)
    if (wid == 2) {
        float val = h2reg * fcw;
        #pragma unroll
        for (int o = 32; o > 0; o >>= 1) val += __shfl_down(val, o, 64);
        if (j == 0) out[b] = val + fc_b[0];
    }
}

extern "C" void kernel_launch(void* const* d_in, const int* in_sizes, int n_in,
                              void* d_out, int out_size, void* d_ws, size_t ws_size,
                              hipStream_t stream) {
    const int*   x     = (const int*)  d_in[0];
    const float* emb   = (const float*)d_in[1];
    const float* W_ih0 = (const float*)d_in[2];
    const float* W_hh0 = (const float*)d_in[3];
    const float* b_ih0 = (const float*)d_in[4];
    const float* b_hh0 = (const float*)d_in[5];
    const float* W_ih1 = (const float*)d_in[6];
    const float* W_hh1 = (const float*)d_in[7];
    const float* b_ih1 = (const float*)d_in[8];
    const float* b_hh1 = (const float*)d_in[9];
    const float* fc_w  = (const float*)d_in[10];
    const float* fc_b  = (const float*)d_in[11];
    float* out  = (float*)d_out;
    float* proj = (float*)d_ws;   // 500*64*4 = 128 KB scratch

    proj_kernel<<<VOCAB, 64, 0, stream>>>(emb, W_ih0, b_ih0, proj);
    rnn_kernel<<<BB, 192, 0, stream>>>(x, proj, W_hh0, b_hh0,
                                       W_ih1, W_hh1, b_ih1, b_hh1,
                                       fc_w, fc_b, out);
}